// Round 5
// baseline (1236.716 us; speedup 1.0000x reference)
//
#include <hip/hip_runtime.h>
#include <cmath>
#include <cstdint>

// Instant-NGP hash encoding: N=2^20 points, D=3, 16 levels, F=2, T=2^19.
// Level-major two-pass. Pair-load trick (prime_x==1) + NT (L1-bypass) table
// gathers: scattered gathers never L1-hit (footprint >= 627KB vs 32KB L1),
// so bypassing L1 avoids the 128B line-fill amplification per request.

constexpr uint32_t kLog2T = 19;
constexpr uint32_t kMask  = (1u << kLog2T) - 1u;
constexpr uint32_t kP1    = 2654435761u;
constexpr uint32_t kP2    = 805459861u;
constexpr uint32_t kN     = 1u << 20;
constexpr uint32_t kL     = 16;

typedef float v2f __attribute__((ext_vector_type(2)));
typedef float v4f __attribute__((ext_vector_type(4)));

__device__ __forceinline__ v2f sel_half(v4f q, uint32_t hi) {
    v2f lo; lo.x = q.x; lo.y = q.y;
    v2f hi2; hi2.x = q.z; hi2.y = q.w;
    return hi ? hi2 : lo;
}

template <bool DIRECT>
__global__ __launch_bounds__(256) void ngp_encode_lm_kernel(
    const float* __restrict__ inp,      // [N,3]
    const v4f* __restrict__ tbl4,       // [16 * 2^18] entry-pairs
    v2f* __restrict__ dst,              // DIRECT: [N,16]; else ws [16,N]
    unsigned long long pk0, unsigned long long pk1,
    unsigned long long pk2, unsigned long long pk3)
{
    const uint32_t b = blockIdx.x;
    const uint32_t l = b >> 12;                         // level-major in time
    const uint32_t n = ((b & 4095u) << 8) + threadIdx.x;

    unsigned long long pk = (l < 8u) ? ((l < 4u) ? pk0 : pk1)
                                     : ((l < 12u) ? pk2 : pk3);
    const float r = (float)((uint32_t)(pk >> ((l & 3u) * 16u)) & 0xFFFFu);

    float x = __builtin_nontemporal_load(inp + n * 3u + 0u);
    float y = __builtin_nontemporal_load(inp + n * 3u + 1u);
    float z = __builtin_nontemporal_load(inp + n * 3u + 2u);
    x = fminf(fmaxf(x, 0.0f), 1.0f);
    y = fminf(fmaxf(y, 0.0f), 1.0f);
    z = fminf(fmaxf(z, 0.0f), 1.0f);

    const float px = x * r, py = y * r, pz = z * r;
    const float fx = floorf(px), fy = floorf(py), fz = floorf(pz);
    const float wx = px - fx, wy = py - fy, wz = pz - fz;

    const uint32_t xi  = (uint32_t)(int)fx;
    const uint32_t xi1 = xi + 1u;
    const uint32_t yi  = (uint32_t)(int)fy;
    const uint32_t zi  = (uint32_t)(int)fz;

    const uint32_t hy0 = yi * kP1, hy1 = hy0 + kP1;
    const uint32_t hz0 = zi * kP2, hz1 = hz0 + kP2;
    const uint32_t hyz00 = hy0 ^ hz0, hyz01 = hy0 ^ hz1;
    const uint32_t hyz10 = hy1 ^ hz0, hyz11 = hy1 ^ hz1;

    const uint32_t pb  = l << (kLog2T - 1);             // pair base (v4f units)
    const uint32_t lb2 = l << kLog2T;                   // entry base (v2f units)
    const v2f* tbl2 = (const v2f*)tbl4;

    const uint32_t i000 = (xi  ^ hyz00) & kMask, i100 = (xi1 ^ hyz00) & kMask;
    const uint32_t i001 = (xi  ^ hyz01) & kMask, i101 = (xi1 ^ hyz01) & kMask;
    const uint32_t i010 = (xi  ^ hyz10) & kMask, i110 = (xi1 ^ hyz10) & kMask;
    const uint32_t i011 = (xi  ^ hyz11) & kMask, i111 = (xi1 ^ hyz11) & kMask;

    // 4 unconditional NT pair loads (cover both x-corners when xi even)
    const v4f q00 = __builtin_nontemporal_load(tbl4 + pb + (i000 >> 1));
    const v4f q01 = __builtin_nontemporal_load(tbl4 + pb + (i001 >> 1));
    const v4f q10 = __builtin_nontemporal_load(tbl4 + pb + (i010 >> 1));
    const v4f q11 = __builtin_nontemporal_load(tbl4 + pb + (i011 >> 1));

    v2f f000 = sel_half(q00, i000 & 1u), f100 = sel_half(q00, (i000 & 1u) ^ 1u);
    v2f f001 = sel_half(q01, i001 & 1u), f101 = sel_half(q01, (i001 & 1u) ^ 1u);
    v2f f010 = sel_half(q10, i010 & 1u), f110 = sel_half(q10, (i010 & 1u) ^ 1u);
    v2f f011 = sel_half(q11, i011 & 1u), f111 = sel_half(q11, (i011 & 1u) ^ 1u);

    if (xi & 1u) {   // odd xi: partner corner = exact 8B NT gather
        f100 = __builtin_nontemporal_load(tbl2 + lb2 + i100);
        f101 = __builtin_nontemporal_load(tbl2 + lb2 + i101);
        f110 = __builtin_nontemporal_load(tbl2 + lb2 + i110);
        f111 = __builtin_nontemporal_load(tbl2 + lb2 + i111);
    }

    const float wx1w = wx, wx0w = 1.0f - wx;
    const float wy1w = wy, wy0w = 1.0f - wy;
    const float wz1w = wz, wz0w = 1.0f - wz;
    const float wyz00w = wy0w * wz0w, wyz01w = wy0w * wz1w;
    const float wyz10w = wy1w * wz0w, wyz11w = wy1w * wz1w;

    float acc0 = 0.0f, acc1 = 0.0f;
#define NGP_ACC(F, W)                         \
    acc0 = fmaf((W), (F).x, acc0);            \
    acc1 = fmaf((W), (F).y, acc1);
    NGP_ACC(f000, wx0w * wyz00w) NGP_ACC(f100, wx1w * wyz00w)
    NGP_ACC(f001, wx0w * wyz01w) NGP_ACC(f101, wx1w * wyz01w)
    NGP_ACC(f010, wx0w * wyz10w) NGP_ACC(f110, wx1w * wyz10w)
    NGP_ACC(f011, wx0w * wyz11w) NGP_ACC(f111, wx1w * wyz11w)
#undef NGP_ACC

    v2f res; res.x = acc0; res.y = acc1;
    if (DIRECT) {
        __builtin_nontemporal_store(res, dst + (n * kL + l));
    } else {
        __builtin_nontemporal_store(res, dst + (l * kN + n));
    }
}

// Transpose ws[16][N] -> out[N][16] (v2f elements), 128 points per block,
// all global IO as 16B nt ops.
__global__ __launch_bounds__(256) void ngp_transpose_kernel(
    const v4f* __restrict__ ws4,      // [16][N/2]
    v4f* __restrict__ out4)           // [N][8]
{
    __shared__ v4f tile4[kL][65];     // [level][point-pair], padded
    const uint32_t t  = threadIdx.x;
    const uint32_t n0 = blockIdx.x * 128u;

    #pragma unroll
    for (uint32_t it = 0; it < 4; ++it) {
        const uint32_t l  = it * 4u + (t >> 6);
        const uint32_t pc = t & 63u;
        tile4[l][pc] = __builtin_nontemporal_load(ws4 + l * (kN / 2u) + (n0 >> 1) + pc);
    }
    __syncthreads();

    const v2f* tv = (const v2f*)&tile4[0][0];     // row stride 130 v2f
    #pragma unroll
    for (uint32_t it = 0; it < 4; ++it) {
        const uint32_t p  = it * 32u + (t >> 3);
        const uint32_t lp = t & 7u;
        const v2f a = tv[(2u * lp + 0u) * 130u + p];
        const v2f b = tv[(2u * lp + 1u) * 130u + p];
        v4f o; o.x = a.x; o.y = a.y; o.z = b.x; o.w = b.y;
        __builtin_nontemporal_store(o, out4 + (n0 + p) * 8u + lp);
    }
}

extern "C" void kernel_launch(void* const* d_in, const int* in_sizes, int n_in,
                              void* d_out, int out_size, void* d_ws, size_t ws_size,
                              hipStream_t stream)
{
    const float* inp = (const float*)d_in[0];
    const v4f* tbl4  = (const v4f*)d_in[1];

    // numpy-exact resolution table (host libm float64 chain)
    double b = std::exp((std::log(512.0) - std::log(16.0)) / 15.0);
    unsigned long long pk[4] = {0ull, 0ull, 0ull, 0ull};
    for (int k = 0; k < 16; ++k) {
        double v;
        if (k == 0)      v = 1.0;
        else if (k == 1) v = b;
        else if (k == 2) v = b * b;
        else             v = std::pow(b, (double)k);
        unsigned long long ri = (unsigned long long)std::floor(16.0 * v);
        pk[k >> 2] |= (ri & 0xFFFFull) << ((k & 3) * 16);
    }

    const uint32_t nblocks = (kN * kL) / 256u;          // 65536
    const bool have_ws = ws_size >= (size_t)kN * kL * sizeof(v2f);

    if (have_ws) {
        hipLaunchKernelGGL((ngp_encode_lm_kernel<false>), dim3(nblocks), dim3(256), 0, stream,
                           inp, tbl4, (v2f*)d_ws, pk[0], pk[1], pk[2], pk[3]);
        hipLaunchKernelGGL(ngp_transpose_kernel, dim3(kN / 128u), dim3(256), 0, stream,
                           (const v4f*)d_ws, (v4f*)d_out);
    } else {
        hipLaunchKernelGGL((ngp_encode_lm_kernel<true>), dim3(nblocks), dim3(256), 0, stream,
                           inp, tbl4, (v2f*)d_out, pk[0], pk[1], pk[2], pk[3]);
    }
}

// Round 6
// 622.663 us; speedup vs baseline: 1.9862x; 1.9862x over previous
//
#include <hip/hip_runtime.h>
#include <cmath>
#include <cstdint>

// Instant-NGP hash encoding: N=2^20 points, D=3, 16 levels, F=2, T=2^19.
// Level-major two-pass. Pair-load trick (prime_x==1). Table gathers use
// buffer_load with sc0 (SE scope): bypass 32KB L1 (which can never hold the
// >=627KB touched footprint) but stay cached in the XCD's 4MB L2 -> no
// 128B line-fill amplification per 8-16B gather. (nt was wrong: it is
// non-temporal at L2 too -> round-5's 2.3GB HBM fetch regression.)

constexpr uint32_t kLog2T = 19;
constexpr uint32_t kMask  = (1u << kLog2T) - 1u;
constexpr uint32_t kP1    = 2654435761u;
constexpr uint32_t kP2    = 805459861u;
constexpr uint32_t kN     = 1u << 20;
constexpr uint32_t kL     = 16;

typedef float v2f __attribute__((ext_vector_type(2)));
typedef float v4f __attribute__((ext_vector_type(4)));
typedef uint32_t v4u __attribute__((ext_vector_type(4)));

__device__ __forceinline__ v2f sel_half(v4f q, uint32_t hi) {
    v2f lo; lo.x = q.x; lo.y = q.y;
    v2f h2; h2.x = q.z; h2.y = q.w;
    return hi ? h2 : lo;
}

template <bool DIRECT>
__global__ __launch_bounds__(256) void ngp_encode_lm_kernel(
    const float* __restrict__ inp,      // [N,3]
    const v4f* __restrict__ tbl4,       // [16 * 2^18] entry-pairs
    v2f* __restrict__ dst,              // DIRECT: [N,16]; else ws [16,N]
    unsigned long long pk0, unsigned long long pk1,
    unsigned long long pk2, unsigned long long pk3)
{
    const uint32_t b = blockIdx.x;
    const uint32_t l = b >> 12;                         // level-major in time
    const uint32_t n = ((b & 4095u) << 8) + threadIdx.x;

    unsigned long long pk = (l < 8u) ? ((l < 4u) ? pk0 : pk1)
                                     : ((l < 12u) ? pk2 : pk3);
    const float r = (float)((uint32_t)(pk >> ((l & 3u) * 16u)) & 0xFFFFu);

    float x = __builtin_nontemporal_load(inp + n * 3u + 0u);
    float y = __builtin_nontemporal_load(inp + n * 3u + 1u);
    float z = __builtin_nontemporal_load(inp + n * 3u + 2u);
    x = fminf(fmaxf(x, 0.0f), 1.0f);
    y = fminf(fmaxf(y, 0.0f), 1.0f);
    z = fminf(fmaxf(z, 0.0f), 1.0f);

    const float px = x * r, py = y * r, pz = z * r;
    const float fx = floorf(px), fy = floorf(py), fz = floorf(pz);
    const float wx = px - fx, wy = py - fy, wz = pz - fz;

    const uint32_t xi  = (uint32_t)(int)fx;
    const uint32_t xi1 = xi + 1u;
    const uint32_t yi  = (uint32_t)(int)fy;
    const uint32_t zi  = (uint32_t)(int)fz;

    const uint32_t hy0 = yi * kP1, hy1 = hy0 + kP1;
    const uint32_t hz0 = zi * kP2, hz1 = hz0 + kP2;
    const uint32_t hyz00 = hy0 ^ hz0, hyz01 = hy0 ^ hz1;
    const uint32_t hyz10 = hy1 ^ hz0, hyz11 = hy1 ^ hz1;

    const uint32_t i000 = (xi  ^ hyz00) & kMask, i100 = (xi1 ^ hyz00) & kMask;
    const uint32_t i001 = (xi  ^ hyz01) & kMask, i101 = (xi1 ^ hyz01) & kMask;
    const uint32_t i010 = (xi  ^ hyz10) & kMask, i110 = (xi1 ^ hyz10) & kMask;
    const uint32_t i011 = (xi  ^ hyz11) & kMask, i111 = (xi1 ^ hyz11) & kMask;

    // SRD for this level's 4MB table slab (uniform per block -> SGPRs)
    const uint64_t ba = (uint64_t)((const char*)tbl4 + ((size_t)l << 22));
    v4u srd;
    srd.x = (uint32_t)ba;
    srd.y = (uint32_t)(ba >> 32);
    srd.z = 0xFFFFFFFFu;        // bounds check disabled (indices are masked)
    srd.w = 0x00020000u;        // raw dword access

    // byte offsets: pair load = (idx & ~1) * 8 ; exact load = idx * 8
    const uint32_t o00 = (i000 & ~1u) << 3, o01 = (i001 & ~1u) << 3;
    const uint32_t o10 = (i010 & ~1u) << 3, o11 = (i011 & ~1u) << 3;

    v4f q00, q01, q10, q11;
    asm volatile(
        "buffer_load_dwordx4 %0, %4, %8, 0 offen sc0\n\t"
        "buffer_load_dwordx4 %1, %5, %8, 0 offen sc0\n\t"
        "buffer_load_dwordx4 %2, %6, %8, 0 offen sc0\n\t"
        "buffer_load_dwordx4 %3, %7, %8, 0 offen sc0\n\t"
        "s_waitcnt vmcnt(0)"
        : "=&v"(q00), "=&v"(q01), "=&v"(q10), "=&v"(q11)
        : "v"(o00), "v"(o01), "v"(o10), "v"(o11), "s"(srd));

    v2f f000 = sel_half(q00, i000 & 1u), f100 = sel_half(q00, (i000 & 1u) ^ 1u);
    v2f f001 = sel_half(q01, i001 & 1u), f101 = sel_half(q01, (i001 & 1u) ^ 1u);
    v2f f010 = sel_half(q10, i010 & 1u), f110 = sel_half(q10, (i010 & 1u) ^ 1u);
    v2f f011 = sel_half(q11, i011 & 1u), f111 = sel_half(q11, (i011 & 1u) ^ 1u);

    if (xi & 1u) {   // odd xi: partner corner = exact 8B gather (exec-masked)
        const uint32_t p00 = i100 << 3, p01 = i101 << 3;
        const uint32_t p10 = i110 << 3, p11 = i111 << 3;
        v2f g00, g01, g10, g11;
        asm volatile(
            "buffer_load_dwordx2 %0, %4, %8, 0 offen sc0\n\t"
            "buffer_load_dwordx2 %1, %5, %8, 0 offen sc0\n\t"
            "buffer_load_dwordx2 %2, %6, %8, 0 offen sc0\n\t"
            "buffer_load_dwordx2 %3, %7, %8, 0 offen sc0\n\t"
            "s_waitcnt vmcnt(0)"
            : "=&v"(g00), "=&v"(g01), "=&v"(g10), "=&v"(g11)
            : "v"(p00), "v"(p01), "v"(p10), "v"(p11), "s"(srd));
        f100 = g00; f101 = g01; f110 = g10; f111 = g11;
    }

    const float wx1w = wx, wx0w = 1.0f - wx;
    const float wy1w = wy, wy0w = 1.0f - wy;
    const float wz1w = wz, wz0w = 1.0f - wz;
    const float wyz00w = wy0w * wz0w, wyz01w = wy0w * wz1w;
    const float wyz10w = wy1w * wz0w, wyz11w = wy1w * wz1w;

    float acc0 = 0.0f, acc1 = 0.0f;
#define NGP_ACC(F, W)                         \
    acc0 = fmaf((W), (F).x, acc0);            \
    acc1 = fmaf((W), (F).y, acc1);
    NGP_ACC(f000, wx0w * wyz00w) NGP_ACC(f100, wx1w * wyz00w)
    NGP_ACC(f001, wx0w * wyz01w) NGP_ACC(f101, wx1w * wyz01w)
    NGP_ACC(f010, wx0w * wyz10w) NGP_ACC(f110, wx1w * wyz10w)
    NGP_ACC(f011, wx0w * wyz11w) NGP_ACC(f111, wx1w * wyz11w)
#undef NGP_ACC

    v2f res; res.x = acc0; res.y = acc1;
    if (DIRECT) {
        __builtin_nontemporal_store(res, dst + (n * kL + l));
    } else {
        __builtin_nontemporal_store(res, dst + (l * kN + n));
    }
}

// Transpose ws[16][N] -> out[N][16] (v2f elements), 128 points per block,
// all global IO as 16B nt ops.
__global__ __launch_bounds__(256) void ngp_transpose_kernel(
    const v4f* __restrict__ ws4,      // [16][N/2]
    v4f* __restrict__ out4)           // [N][8]
{
    __shared__ v4f tile4[kL][65];     // [level][point-pair], padded
    const uint32_t t  = threadIdx.x;
    const uint32_t n0 = blockIdx.x * 128u;

    #pragma unroll
    for (uint32_t it = 0; it < 4; ++it) {
        const uint32_t l  = it * 4u + (t >> 6);
        const uint32_t pc = t & 63u;
        tile4[l][pc] = __builtin_nontemporal_load(ws4 + l * (kN / 2u) + (n0 >> 1) + pc);
    }
    __syncthreads();

    const v2f* tv = (const v2f*)&tile4[0][0];     // row stride 130 v2f
    #pragma unroll
    for (uint32_t it = 0; it < 4; ++it) {
        const uint32_t p  = it * 32u + (t >> 3);
        const uint32_t lp = t & 7u;
        const v2f a = tv[(2u * lp + 0u) * 130u + p];
        const v2f b = tv[(2u * lp + 1u) * 130u + p];
        v4f o; o.x = a.x; o.y = a.y; o.z = b.x; o.w = b.y;
        __builtin_nontemporal_store(o, out4 + (n0 + p) * 8u + lp);
    }
}

extern "C" void kernel_launch(void* const* d_in, const int* in_sizes, int n_in,
                              void* d_out, int out_size, void* d_ws, size_t ws_size,
                              hipStream_t stream)
{
    const float* inp = (const float*)d_in[0];
    const v4f* tbl4  = (const v4f*)d_in[1];

    // numpy-exact resolution table (host libm float64 chain)
    double b = std::exp((std::log(512.0) - std::log(16.0)) / 15.0);
    unsigned long long pk[4] = {0ull, 0ull, 0ull, 0ull};
    for (int k = 0; k < 16; ++k) {
        double v;
        if (k == 0)      v = 1.0;
        else if (k == 1) v = b;
        else if (k == 2) v = b * b;
        else             v = std::pow(b, (double)k);
        unsigned long long ri = (unsigned long long)std::floor(16.0 * v);
        pk[k >> 2] |= (ri & 0xFFFFull) << ((k & 3) * 16);
    }

    const uint32_t nblocks = (kN * kL) / 256u;          // 65536
    const bool have_ws = ws_size >= (size_t)kN * kL * sizeof(v2f);

    if (have_ws) {
        hipLaunchKernelGGL((ngp_encode_lm_kernel<false>), dim3(nblocks), dim3(256), 0, stream,
                           inp, tbl4, (v2f*)d_ws, pk[0], pk[1], pk[2], pk[3]);
        hipLaunchKernelGGL(ngp_transpose_kernel, dim3(kN / 128u), dim3(256), 0, stream,
                           (const v4f*)d_ws, (v4f*)d_out);
    } else {
        hipLaunchKernelGGL((ngp_encode_lm_kernel<true>), dim3(nblocks), dim3(256), 0, stream,
                           inp, tbl4, (v2f*)d_out, pk[0], pk[1], pk[2], pk[3]);
    }
}

// Round 8
// 555.348 us; speedup vs baseline: 2.2269x; 1.1212x over previous
//
#include <hip/hip_runtime.h>
#include <cmath>
#include <cstdint>

// Instant-NGP hash encoding: N=2^20 points, D=3, 16 levels, F=2, T=2^19.
// v7: spatial counting-sort (4096 cells, 4bit/dim) -> level-major encode on
// sorted points. Within a wave, 64 spatially-adjacent points share table
// cache lines (hash keeps x-contiguity since prime_x==1), so the TA merges
// lane requests -> attacks the L2 scattered-request-rate wall identified in
// rounds 4-6 (sc0 null, nt catastrophic => request-count bound).

constexpr uint32_t kLog2T = 19;
constexpr uint32_t kMask  = (1u << kLog2T) - 1u;
constexpr uint32_t kP1    = 2654435761u;
constexpr uint32_t kP2    = 805459861u;
constexpr uint32_t kN     = 1u << 20;
constexpr uint32_t kL     = 16;
constexpr uint32_t kBins  = 4096;

typedef float v2f __attribute__((ext_vector_type(2)));
typedef float v4f __attribute__((ext_vector_type(4)));
typedef uint32_t v4u __attribute__((ext_vector_type(4)));

__device__ __forceinline__ v2f sel_half(v4f q, uint32_t hi) {
    v2f lo; lo.x = q.x; lo.y = q.y;
    v2f h2; h2.x = q.z; h2.y = q.w;
    return hi ? h2 : lo;
}

__device__ __forceinline__ uint32_t cell_key(float x, float y, float z) {
    uint32_t qx = (uint32_t)(x * 16.0f); qx = qx > 15u ? 15u : qx;
    uint32_t qy = (uint32_t)(y * 16.0f); qy = qy > 15u ? 15u : qy;
    uint32_t qz = (uint32_t)(z * 16.0f); qz = qz > 15u ? 15u : qz;
    return (qz << 8) | (qy << 4) | qx;
}

// ---- sort pipeline -------------------------------------------------------

__global__ __launch_bounds__(1024) void ngp_hist_kernel(
    const float* __restrict__ inp, uint32_t* __restrict__ bins)
{
    __shared__ uint32_t h[kBins];
    const uint32_t t = threadIdx.x;
    for (uint32_t i = t; i < kBins; i += 1024u) h[i] = 0u;
    __syncthreads();
    const uint32_t base = blockIdx.x * 1024u * 16u;
    #pragma unroll 4
    for (uint32_t k = 0; k < 16u; ++k) {
        const uint32_t n = base + k * 1024u + t;
        float x = fminf(fmaxf(inp[n * 3u + 0u], 0.0f), 1.0f);
        float y = fminf(fmaxf(inp[n * 3u + 1u], 0.0f), 1.0f);
        float z = fminf(fmaxf(inp[n * 3u + 2u], 0.0f), 1.0f);
        atomicAdd(&h[cell_key(x, y, z)], 1u);
    }
    __syncthreads();
    for (uint32_t i = t; i < kBins; i += 1024u)
        if (h[i]) atomicAdd(&bins[i], h[i]);
}

__global__ __launch_bounds__(64) void ngp_scan_kernel(
    const uint32_t* __restrict__ bins, uint32_t* __restrict__ cursor)
{
    const uint32_t t = threadIdx.x;          // one wave; 64 bins per lane
    uint32_t s = 0u;
    for (uint32_t i = 0; i < 64u; ++i) s += bins[t * 64u + i];
    uint32_t pre = s;
    for (int d = 1; d < 64; d <<= 1) {
        uint32_t u = __shfl_up(pre, d);
        if ((int)t >= d) pre += u;
    }
    pre -= s;                                 // exclusive prefix of chunk
    for (uint32_t i = 0; i < 64u; ++i) {
        cursor[t * 64u + i] = pre;
        pre += bins[t * 64u + i];
    }
}

__global__ __launch_bounds__(256) void ngp_scatter_kernel(
    const float* __restrict__ inp, uint32_t* __restrict__ cursor,
    v4f* __restrict__ sorted)
{
    const uint32_t n = blockIdx.x * 256u + threadIdx.x;
    float x = fminf(fmaxf(inp[n * 3u + 0u], 0.0f), 1.0f);
    float y = fminf(fmaxf(inp[n * 3u + 1u], 0.0f), 1.0f);
    float z = fminf(fmaxf(inp[n * 3u + 2u], 0.0f), 1.0f);
    const uint32_t key = cell_key(x, y, z);
    const uint32_t pos = atomicAdd(&cursor[key], 1u);
    v4f s; s.x = x; s.y = y; s.z = z; s.w = __uint_as_float(n);
    sorted[pos] = s;
}

// ---- encode (8 levels per pass, sorted order) ----------------------------

template <uint32_t BASE>
__global__ __launch_bounds__(256) void ngp_encode_sorted_kernel(
    const v4f* __restrict__ sorted,     // [N] {x,y,z,orig}
    const v4f* __restrict__ tbl4,       // [16 * 2^18] entry-pairs
    v2f* __restrict__ wsres,            // [8][N]
    unsigned long long pk0, unsigned long long pk1,
    unsigned long long pk2, unsigned long long pk3)
{
    const uint32_t b = blockIdx.x;
    const uint32_t l = BASE + (b >> 12);
    const uint32_t j = ((b & 4095u) << 8) + threadIdx.x;

    unsigned long long pk = (l < 8u) ? ((l < 4u) ? pk0 : pk1)
                                     : ((l < 12u) ? pk2 : pk3);
    const float r = (float)((uint32_t)(pk >> ((l & 3u) * 16u)) & 0xFFFFu);

    const v4f s = sorted[j];            // pre-clamped
    const float px = s.x * r, py = s.y * r, pz = s.z * r;
    const float fx = floorf(px), fy = floorf(py), fz = floorf(pz);
    const float wx = px - fx, wy = py - fy, wz = pz - fz;

    const uint32_t xi  = (uint32_t)(int)fx;
    const uint32_t xi1 = xi + 1u;
    const uint32_t yi  = (uint32_t)(int)fy;
    const uint32_t zi  = (uint32_t)(int)fz;

    const uint32_t hy0 = yi * kP1, hy1 = hy0 + kP1;
    const uint32_t hz0 = zi * kP2, hz1 = hz0 + kP2;
    const uint32_t hyz00 = hy0 ^ hz0, hyz01 = hy0 ^ hz1;
    const uint32_t hyz10 = hy1 ^ hz0, hyz11 = hy1 ^ hz1;

    const uint32_t i000 = (xi  ^ hyz00) & kMask, i100 = (xi1 ^ hyz00) & kMask;
    const uint32_t i001 = (xi  ^ hyz01) & kMask, i101 = (xi1 ^ hyz01) & kMask;
    const uint32_t i010 = (xi  ^ hyz10) & kMask, i110 = (xi1 ^ hyz10) & kMask;
    const uint32_t i011 = (xi  ^ hyz11) & kMask, i111 = (xi1 ^ hyz11) & kMask;

    const uint64_t ba = (uint64_t)((const char*)tbl4 + ((size_t)l << 22));
    v4u srd;
    srd.x = (uint32_t)ba;
    srd.y = (uint32_t)(ba >> 32);
    srd.z = 0xFFFFFFFFu;
    srd.w = 0x00020000u;

    const uint32_t o00 = (i000 & ~1u) << 3, o01 = (i001 & ~1u) << 3;
    const uint32_t o10 = (i010 & ~1u) << 3, o11 = (i011 & ~1u) << 3;

    v4f q00, q01, q10, q11;
    asm volatile(
        "buffer_load_dwordx4 %0, %4, %8, 0 offen sc0\n\t"
        "buffer_load_dwordx4 %1, %5, %8, 0 offen sc0\n\t"
        "buffer_load_dwordx4 %2, %6, %8, 0 offen sc0\n\t"
        "buffer_load_dwordx4 %3, %7, %8, 0 offen sc0\n\t"
        "s_waitcnt vmcnt(0)"
        : "=&v"(q00), "=&v"(q01), "=&v"(q10), "=&v"(q11)
        : "v"(o00), "v"(o01), "v"(o10), "v"(o11), "s"(srd));

    v2f f000 = sel_half(q00, i000 & 1u), f100 = sel_half(q00, (i000 & 1u) ^ 1u);
    v2f f001 = sel_half(q01, i001 & 1u), f101 = sel_half(q01, (i001 & 1u) ^ 1u);
    v2f f010 = sel_half(q10, i010 & 1u), f110 = sel_half(q10, (i010 & 1u) ^ 1u);
    v2f f011 = sel_half(q11, i011 & 1u), f111 = sel_half(q11, (i011 & 1u) ^ 1u);

    if (xi & 1u) {
        const uint32_t p00 = i100 << 3, p01 = i101 << 3;
        const uint32_t p10 = i110 << 3, p11 = i111 << 3;
        v2f g00, g01, g10, g11;
        asm volatile(
            "buffer_load_dwordx2 %0, %4, %8, 0 offen sc0\n\t"
            "buffer_load_dwordx2 %1, %5, %8, 0 offen sc0\n\t"
            "buffer_load_dwordx2 %2, %6, %8, 0 offen sc0\n\t"
            "buffer_load_dwordx2 %3, %7, %8, 0 offen sc0\n\t"
            "s_waitcnt vmcnt(0)"
            : "=&v"(g00), "=&v"(g01), "=&v"(g10), "=&v"(g11)
            : "v"(p00), "v"(p01), "v"(p10), "v"(p11), "s"(srd));
        f100 = g00; f101 = g01; f110 = g10; f111 = g11;
    }

    const float wx1w = wx, wx0w = 1.0f - wx;
    const float wy1w = wy, wy0w = 1.0f - wy;
    const float wz1w = wz, wz0w = 1.0f - wz;
    const float wyz00w = wy0w * wz0w, wyz01w = wy0w * wz1w;
    const float wyz10w = wy1w * wz0w, wyz11w = wy1w * wz1w;

    float acc0 = 0.0f, acc1 = 0.0f;
#define NGP_ACC(F, W)                         \
    acc0 = fmaf((W), (F).x, acc0);            \
    acc1 = fmaf((W), (F).y, acc1);
    NGP_ACC(f000, wx0w * wyz00w) NGP_ACC(f100, wx1w * wyz00w)
    NGP_ACC(f001, wx0w * wyz01w) NGP_ACC(f101, wx1w * wyz01w)
    NGP_ACC(f010, wx0w * wyz10w) NGP_ACC(f110, wx1w * wyz10w)
    NGP_ACC(f011, wx0w * wyz11w) NGP_ACC(f111, wx1w * wyz11w)
#undef NGP_ACC

    v2f res; res.x = acc0; res.y = acc1;
    __builtin_nontemporal_store(res, wsres + (l - BASE) * kN + j);
}

// Un-permute + transpose: ws[8][N](sorted) -> out[orig][levels BASE..BASE+7].
// Each point's 8 levels = 64B contiguous -> line-granular scatter writes.
template <uint32_t BASE>
__global__ __launch_bounds__(256) void ngp_untrans_kernel(
    const v4f* __restrict__ ws4,        // [8][N/2]
    const v4f* __restrict__ sorted,     // .w = orig index
    v4f* __restrict__ out4)             // [N][8]
{
    __shared__ v4f tile4[8][65];
    const uint32_t t  = threadIdx.x;
    const uint32_t j0 = blockIdx.x * 128u;

    #pragma unroll
    for (uint32_t it = 0; it < 2; ++it) {
        const uint32_t lo = it * 4u + (t >> 6);
        const uint32_t pc = t & 63u;
        tile4[lo][pc] = ws4[lo * (kN / 2u) + (j0 >> 1) + pc];
    }
    __syncthreads();

    const v2f* tv = (const v2f*)&tile4[0][0];    // row stride 130 v2f
    #pragma unroll
    for (uint32_t it = 0; it < 2; ++it) {
        const uint32_t p  = it * 64u + (t >> 2);
        const uint32_t lp = t & 3u;
        const v2f a = tv[(2u * lp + 0u) * 130u + p];
        const v2f b = tv[(2u * lp + 1u) * 130u + p];
        v4f o; o.x = a.x; o.y = a.y; o.z = b.x; o.w = b.y;
        const uint32_t orig = __float_as_uint(sorted[j0 + p].w);
        __builtin_nontemporal_store(o, out4 + orig * 8u + (BASE / 2u) + lp);
    }
}

// ---- fallback (no/small ws): direct strided, unsorted --------------------

__global__ __launch_bounds__(256) void ngp_encode_direct_kernel(
    const float* __restrict__ inp, const v4f* __restrict__ tbl4,
    v2f* __restrict__ dst,
    unsigned long long pk0, unsigned long long pk1,
    unsigned long long pk2, unsigned long long pk3)
{
    const uint32_t b = blockIdx.x;
    const uint32_t l = b >> 12;
    const uint32_t n = ((b & 4095u) << 8) + threadIdx.x;
    unsigned long long pk = (l < 8u) ? ((l < 4u) ? pk0 : pk1)
                                     : ((l < 12u) ? pk2 : pk3);
    const float r = (float)((uint32_t)(pk >> ((l & 3u) * 16u)) & 0xFFFFu);
    float x = fminf(fmaxf(inp[n * 3u + 0u], 0.0f), 1.0f);
    float y = fminf(fmaxf(inp[n * 3u + 1u], 0.0f), 1.0f);
    float z = fminf(fmaxf(inp[n * 3u + 2u], 0.0f), 1.0f);
    const float px = x * r, py = y * r, pz = z * r;
    const float fx = floorf(px), fy = floorf(py), fz = floorf(pz);
    const float wx = px - fx, wy = py - fy, wz = pz - fz;
    const uint32_t xi = (uint32_t)(int)fx, yi = (uint32_t)(int)fy, zi = (uint32_t)(int)fz;
    const uint32_t hy0 = yi * kP1, hy1 = hy0 + kP1;
    const uint32_t hz0 = zi * kP2, hz1 = hz0 + kP2;
    const v2f* tbl2 = (const v2f*)tbl4;
    const uint32_t lb2 = l << kLog2T;
    float acc0 = 0.0f, acc1 = 0.0f;
#define NGP_C(HX, HY, HZ, W)                                        \
    {                                                               \
        uint32_t h = ((HX) ^ (HY) ^ (HZ)) & kMask;                  \
        v2f f = tbl2[lb2 + h];                                      \
        acc0 = fmaf((W), f.x, acc0); acc1 = fmaf((W), f.y, acc1);   \
    }
    const float wxa = 1.0f - wx, wya = 1.0f - wy, wza = 1.0f - wz;
    NGP_C(xi,      hy0, hz0, wxa * wya * wza) NGP_C(xi + 1u, hy0, hz0, wx * wya * wza)
    NGP_C(xi,      hy0, hz1, wxa * wya * wz ) NGP_C(xi + 1u, hy0, hz1, wx * wya * wz )
    NGP_C(xi,      hy1, hz0, wxa * wy  * wza) NGP_C(xi + 1u, hy1, hz0, wx * wy  * wza)
    NGP_C(xi,      hy1, hz1, wxa * wy  * wz ) NGP_C(xi + 1u, hy1, hz1, wx * wy  * wz )
#undef NGP_C
    v2f res; res.x = acc0; res.y = acc1;
    dst[n * kL + l] = res;
}

extern "C" void kernel_launch(void* const* d_in, const int* in_sizes, int n_in,
                              void* d_out, int out_size, void* d_ws, size_t ws_size,
                              hipStream_t stream)
{
    const float* inp = (const float*)d_in[0];
    const v4f* tbl4  = (const v4f*)d_in[1];

    // numpy-exact resolution table (host libm float64 chain)
    double b = std::exp((std::log(512.0) - std::log(16.0)) / 15.0);
    unsigned long long pk[4] = {0ull, 0ull, 0ull, 0ull};
    for (int k = 0; k < 16; ++k) {
        double v;
        if (k == 0)      v = 1.0;
        else if (k == 1) v = b;
        else if (k == 2) v = b * b;
        else             v = std::pow(b, (double)k);
        unsigned long long ri = (unsigned long long)std::floor(16.0 * v);
        pk[k >> 2] |= (ri & 0xFFFFull) << ((k & 3) * 16);
    }

    // ws layout: sorted v4f[N] (16MB) | bins u32[4096] | cursor u32[4096] | wsres v2f[8][N] (64MB)
    const size_t offSorted = 0;
    const size_t offBins   = (size_t)16 * 1024 * 1024;
    const size_t offCursor = offBins + kBins * sizeof(uint32_t);
    const size_t offRes    = offBins + 65536;
    const size_t need      = offRes + (size_t)8 * kN * sizeof(v2f);

    if (ws_size >= need) {
        char* w = (char*)d_ws;
        v4f*      sorted = (v4f*)(w + offSorted);
        uint32_t* bins   = (uint32_t*)(w + offBins);
        uint32_t* cursor = (uint32_t*)(w + offCursor);
        v2f*      wsres  = (v2f*)(w + offRes);

        hipMemsetAsync(bins, 0, kBins * sizeof(uint32_t), stream);
        hipLaunchKernelGGL(ngp_hist_kernel, dim3(64), dim3(1024), 0, stream, inp, bins);
        hipLaunchKernelGGL(ngp_scan_kernel, dim3(1), dim3(64), 0, stream, bins, cursor);
        hipLaunchKernelGGL(ngp_scatter_kernel, dim3(kN / 256u), dim3(256), 0, stream,
                           inp, cursor, sorted);

        hipLaunchKernelGGL((ngp_encode_sorted_kernel<0>), dim3(32768), dim3(256), 0, stream,
                           sorted, tbl4, wsres, pk[0], pk[1], pk[2], pk[3]);
        hipLaunchKernelGGL((ngp_untrans_kernel<0>), dim3(kN / 128u), dim3(256), 0, stream,
                           (const v4f*)wsres, sorted, (v4f*)d_out);
        hipLaunchKernelGGL((ngp_encode_sorted_kernel<8>), dim3(32768), dim3(256), 0, stream,
                           sorted, tbl4, wsres, pk[0], pk[1], pk[2], pk[3]);
        hipLaunchKernelGGL((ngp_untrans_kernel<8>), dim3(kN / 128u), dim3(256), 0, stream,
                           (const v4f*)wsres, sorted, (v4f*)d_out);
    } else {
        hipLaunchKernelGGL(ngp_encode_direct_kernel, dim3((kN * kL) / 256u), dim3(256), 0, stream,
                           inp, tbl4, (v2f*)d_out, pk[0], pk[1], pk[2], pk[3]);
    }
}